// Round 3
// baseline (704.841 us; speedup 1.0000x reference)
//
#include <hip/hip_runtime.h>
#include <math.h>

#define NN_ 32768      // nodes
#define NE_ 49152      // edges
#define NG_ 1024       // graphs

typedef short bh8 __attribute__((ext_vector_type(8)));   // 8 bf16 bit-patterns (4 VGPR)
typedef float f32x4 __attribute__((ext_vector_type(4)));

__device__ __forceinline__ unsigned short f2bfu(float f) {   // RNE float->bf16 bits
    union { float f; unsigned int i; } x; x.f = f;
    unsigned int u = x.i;
    u += 0x7FFFu + ((u >> 16) & 1u);
    return (unsigned short)(u >> 16);
}
__device__ __forceinline__ float sigm(float x) { return 1.f / (1.f + expf(-x)); }

// Kept for harness compatibility (unused).
__global__ void MPNN_78632261256134_kernel() {}

// ---------------- zero fill ----------------
__global__ void k_zero(float* p, int n) {
    int i = blockIdx.x * 256 + threadIdx.x;
    if (i < n) p[i] = 0.f;
}

// ---------------- fused init zero: cnt (NN_) + qstar|hl|cl (NG_*256) ----------------
__global__ void k_init(float* cnt, float* qstar) {
    int i = blockIdx.x * 256 + threadIdx.x;
    if (i < NN_) cnt[i] = 0.f;
    else if (i < NN_ + NG_ * 256) qstar[i - NN_] = 0.f;
}

// ---------------- lin0 ----------------
__global__ void k_lin0(const float* x, const float* W, const float* b, float* node) {
    int g = blockIdx.x * 256 + threadIdx.x;   // n*64+d
    int n = g >> 6, d = g & 63;
    const float* xr = x + n * 14;
    const float* wr = W + d * 14;
    float acc = b[d];
    for (int i = 0; i < 14; i++) acc += xr[i] * wr[i];
    node[g] = fmaxf(acc, 0.f);
}

// ---------------- in-degree count ----------------
__global__ void k_cnt(const int* dst, float* cnt) {
    int e = blockIdx.x * 256 + threadIdx.x;
    if (e < NE_) atomicAdd(&cnt[dst[e]], 1.0f);
}

// ---------------- fused weight transposes (4 kernels -> 1) ----------------
// [0,12288): gWih [192,64]->WihT [64,192]; [12288,24576): gWhh likewise;
// [24576,57344): lWih [256,128]->WihT2 [128,256]; [57344,73728): lWhh [256,64]->WhhT2 [64,256]
__global__ void k_tw(const float* gWih, const float* gWhh, float* WihT, float* WhhT,
                     const float* lWih, const float* lWhh, float* WihT2, float* WhhT2) {
    int t = blockIdx.x * 256 + threadIdx.x;
    if (t < 12288) {
        int gr = t >> 6, i = t & 63; WihT[i * 192 + gr] = gWih[t];
    } else if (t < 24576) {
        int u = t - 12288; int gr = u >> 6, i = u & 63; WhhT[i * 192 + gr] = gWhh[u];
    } else if (t < 57344) {
        int u = t - 24576; int r = u >> 7, c = u & 127; WihT2[c * 256 + r] = lWih[u];
    } else if (t < 73728) {
        int u = t - 57344; int r = u >> 6, c = u & 63; WhhT2[c * 256 + r] = lWhh[u];
    }
}

// ---------------- Bhat3: frag-contiguous bf16 B [s][w][t][lane][8] ----------------
__global__ void k_bhat3(const float* e2W, unsigned short* Bhat3) {
    int idx = blockIdx.x * 256 + threadIdx.x;   // < 524288
    if (idx >= 64 * 4 * 4 * 64 * 8) return;
    int j = idx & 7, lane = (idx >> 3) & 63, t = (idx >> 9) & 3, w = (idx >> 11) & 3, s = idx >> 13;
    int row = s * 64 + w * 16 + (lane & 15);
    int k = t * 32 + (lane >> 4) * 8 + j;
    Bhat3[idx] = f2bfu(e2W[row * 128 + k]);
}

// ---------------- Hhat: frag-ready He (iteration-invariant, computed once) ----------------
// gi = etile*4+t; grid must cover gi < (NE_/16)*4 = 12288 -> NE_/16 blocks of 4 gi.
__global__ __launch_bounds__(256) void k_he(const float* __restrict__ ea,
                                            const float* __restrict__ e1W,
                                            const float* __restrict__ e1b,
                                            unsigned short* __restrict__ Hhat) {
    int tid = threadIdx.x;
    int lane = tid & 63, sub = tid >> 6;
    int gi = blockIdx.x * 4 + sub;            // < 12288
    int etile = gi >> 2, t = gi & 3;
    int e = etile * 16 + (lane & 15), quad = lane >> 4;
    const float* ar = ea + (size_t)e * 4;
    float a0 = ar[0], a1 = ar[1], a2 = ar[2], a3 = ar[3];
    union { unsigned short u[8]; uint4 q; } o;
#pragma unroll
    for (int j = 0; j < 8; j++) {
        int c = t * 32 + quad * 8 + j;
        const float* wr = e1W + c * 4;
        float h = e1b[c] + a0 * wr[0] + a1 * wr[1] + a2 * wr[2] + a3 * wr[3];
        o.u[j] = f2bfu(fmaxf(h, 0.f));
    }
    *(uint4*)(Hhat + (size_t)gi * 512 + lane * 8) = o.q;
}

// ---------------- MFMA NNConv, K(t)-split across 2 blocks per edge-tile ----------------
// bid = etile*2 + t0; block handles MFMA K-tiles t in {2*t0, 2*t0+1} (half the edge-MLP
// hidden dim). af[4][2] halves the A-fragment register set (64 -> 32 VGPRs) so the
// unified VGPR+AGPR total fits 4 waves/SIMD (16 waves/CU), vs the previous 8-waves/CU cap.
// msg = sum_t [sum_s xv*acc_t] + sum_s xv*bb; bias term added by the t0==0 block only.
// s-loop unrolled by 2 with alternating b0/b1 prefetch buffers (no per-iter reg copies).
#define CONV_STEP(BREG, BBIAS, SIDX, WITH_BIAS)                                          \
    {                                                                                    \
        f32x4 acc[4];                                                                    \
        _Pragma("unroll")                                                                \
        for (int mt = 0; mt < 4; mt++)                                                   \
            acc[mt] = __builtin_amdgcn_mfma_f32_16x16x32_bf16(af[mt][0], BREG[0], z4, 0, 0, 0); \
        _Pragma("unroll")                                                                \
        for (int mt = 0; mt < 4; mt++)                                                   \
            acc[mt] = __builtin_amdgcn_mfma_f32_16x16x32_bf16(af[mt][1], BREG[1], acc[mt], 0, 0, 0); \
        _Pragma("unroll")                                                                \
        for (int mt = 0; mt < 4; mt++) {                                                 \
            f32x4 xv = *(const f32x4*)(const void*)(xs + (SIDX) * 68 + mt * 16 + quad * 4); \
            _Pragma("unroll")                                                            \
            for (int r = 0; r < 4; r++)                                                  \
                msg[mt][r] += xv[r] * (WITH_BIAS ? (acc[mt][r] + (BBIAS)) : acc[mt][r]); \
        }                                                                                \
    }

__global__ __launch_bounds__(256, 4) void k_convr(const float* __restrict__ node,
                                                  const unsigned short* __restrict__ Hhat,
                                                  const unsigned short* __restrict__ Bhat3,
                                                  const float* __restrict__ e2b,
                                                  const int* __restrict__ src,
                                                  const int* __restrict__ dst,
                                                  float* __restrict__ agg) {
    __shared__ __align__(16) float xs[64 * 68];   // xs[s][e]
    __shared__ int dst_s[64];

    const int tid = threadIdx.x;
    const int bid = blockIdx.x;
    const int etile = bid >> 1, t0 = bid & 1;
    const int eb = etile * 64;
    const int lane = tid & 63, w = tid >> 6;
    const int quad = lane >> 4, mrow = lane & 15;

    {   // stage x[src] transposed: 4 threads/edge, 16 dims each
        int r = tid >> 2, c = tid & 3;
        int s = src[eb + r];
        const float* nr = node + (size_t)s * 64 + c * 16;
#pragma unroll
        for (int j = 0; j < 16; j++) xs[(c * 16 + j) * 68 + r] = nr[j];
        if (tid < 64) dst_s[tid] = dst[eb + tid];
    }

    bh8 af[4][2];   // A fragments for this block's 2 K-tiles only
#pragma unroll
    for (int mt = 0; mt < 4; mt++)
#pragma unroll
        for (int tt = 0; tt < 2; tt++)
            af[mt][tt] = *(const bh8*)(const void*)(
                Hhat + (size_t)(((eb >> 4) + mt) * 4 + t0 * 2 + tt) * 512 + lane * 8);
    __syncthreads();   // the ONLY barrier

    const f32x4 z4 = {0.f, 0.f, 0.f, 0.f};
    f32x4 msg[4];
#pragma unroll
    for (int mt = 0; mt < 4; mt++) msg[mt] = z4;

    // B walk: offset(s,tt) = s*8192 + (w*4 + t0*2 + tt)*512 + lane*8  (shorts)
    const unsigned short* __restrict__ bp =
        Bhat3 + (size_t)(w * 4 + t0 * 2) * 512 + lane * 8;

    bh8 b0[2], b1[2];
    b0[0] = *(const bh8*)(const void*)(bp);
    b0[1] = *(const bh8*)(const void*)(bp + 512);

    if (t0 == 0) {
        const float* __restrict__ ebp = e2b + w * 16 + mrow;
        float bb0 = ebp[0], bb1;
        for (int s = 0; s < 64; s += 2) {
            b1[0] = *(const bh8*)(const void*)(bp + 8192);
            b1[1] = *(const bh8*)(const void*)(bp + 8192 + 512);
            bb1 = ebp[64];
            CONV_STEP(b0, bb0, s, 1)
            bp += 16384; ebp += 128;
            if (s + 2 < 64) {
                b0[0] = *(const bh8*)(const void*)(bp);
                b0[1] = *(const bh8*)(const void*)(bp + 512);
                bb0 = ebp[0];
            }
            CONV_STEP(b1, bb1, s + 1, 1)
        }
    } else {
        for (int s = 0; s < 64; s += 2) {
            b1[0] = *(const bh8*)(const void*)(bp + 8192);
            b1[1] = *(const bh8*)(const void*)(bp + 8192 + 512);
            CONV_STEP(b0, 0.f, s, 0)
            bp += 16384;
            if (s + 2 < 64) {
                b0[0] = *(const bh8*)(const void*)(bp);
                b0[1] = *(const bh8*)(const void*)(bp + 512);
            }
            CONV_STEP(b1, 0.f, s + 1, 0)
        }
    }

#pragma unroll
    for (int mt = 0; mt < 4; mt++)
#pragma unroll
        for (int r = 0; r < 4; r++)
            atomicAdd(agg + (size_t)dst_s[mt * 16 + quad * 4 + r] * 64 + w * 16 + mrow,
                      msg[mt][r]);
}

// ---------------- fused m+GRU, transposed LDS (broadcast b128 reads) ----------------
// 16 nodes/block, thread (sub=tid>>6, d=tid&63) handles nodes sub*4..+3 at dim d.
// msT/hsT are [i][node] stride 20 -> wave-wide reads of msT[i][r0..r0+3] are broadcast b128.
__global__ __launch_bounds__(256) void k_mgru(const float* __restrict__ agg,
                                              const float* __restrict__ cnt,
                                              const float* __restrict__ node,
                                              const float* __restrict__ rootW,
                                              const float* __restrict__ convb,
                                              const float* __restrict__ WihT,
                                              const float* __restrict__ WhhT,
                                              const float* __restrict__ bih,
                                              const float* __restrict__ bhh,
                                              float* __restrict__ hOut) {
    __shared__ __align__(16) float hsT[64][20];   // hsT[i][node]
    __shared__ __align__(16) float msT[64][20];
    const int tid = threadIdx.x;
    const int d = tid & 63, sub = tid >> 6;
    const int nb = blockIdx.x * 16;
    const int r0 = sub * 4;

    {   // stage h transposed: coalesced global reads, one b128 LDS store
        f32x4 hv;
#pragma unroll
        for (int j = 0; j < 4; j++)
            hv[j] = node[(size_t)(nb + r0 + j) * 64 + d];
        *(f32x4*)&hsT[d][r0] = hv;
    }
    __syncthreads();

    {   // m = relu(agg/cnt + h@rootW + convb); rootW load shared, hsT broadcast
        f32x4 root = {0.f, 0.f, 0.f, 0.f};
        for (int i = 0; i < 64; i++) {
            float wv = rootW[i * 64 + d];
            f32x4 h4 = *(const f32x4*)&hsT[i][r0];
#pragma unroll
            for (int j = 0; j < 4; j++) root[j] += h4[j] * wv;
        }
        float cb = convb[d];
        f32x4 mval;
#pragma unroll
        for (int j = 0; j < 4; j++) {
            int n = nb + r0 + j;
            float inv = 1.f / fmaxf(cnt[n], 1.f);
            mval[j] = fmaxf(agg[(size_t)n * 64 + d] * inv + cb + root[j], 0.f);
        }
        *(f32x4*)&msT[d][r0] = mval;
    }
    __syncthreads();

    float ir[4], iz[4], in_[4], hr[4], hz[4], hn[4];
    {
        float bi0 = bih[d], bi1 = bih[64 + d], bi2 = bih[128 + d];
        float bh0 = bhh[d], bh1 = bhh[64 + d], bh2 = bhh[128 + d];
#pragma unroll
        for (int j = 0; j < 4; j++) {
            ir[j] = bi0; iz[j] = bi1; in_[j] = bi2;
            hr[j] = bh0; hz[j] = bh1; hn[j] = bh2;
        }
    }
    for (int i = 0; i < 64; i++) {
        float wi0 = WihT[i * 192 + d];
        float wi1 = WihT[i * 192 + 64 + d];
        float wi2 = WihT[i * 192 + 128 + d];
        float wh0 = WhhT[i * 192 + d];
        float wh1 = WhhT[i * 192 + 64 + d];
        float wh2 = WhhT[i * 192 + 128 + d];
        f32x4 m4 = *(const f32x4*)&msT[i][r0];   // broadcast
        f32x4 h4 = *(const f32x4*)&hsT[i][r0];   // broadcast
#pragma unroll
        for (int j = 0; j < 4; j++) {
            ir[j] += m4[j] * wi0; iz[j] += m4[j] * wi1; in_[j] += m4[j] * wi2;
            hr[j] += h4[j] * wh0; hz[j] += h4[j] * wh1; hn[j] += h4[j] * wh2;
        }
    }
    f32x4 hold = *(const f32x4*)&hsT[d][r0];
#pragma unroll
    for (int j = 0; j < 4; j++) {
        float r = sigm(ir[j] + hr[j]);
        float z = sigm(iz[j] + hz[j]);
        float nn = tanhf(in_[j] + r * hn[j]);
        hOut[(size_t)(nb + r0 + j) * 64 + d] = (1.f - z) * nn + z * hold[j];
    }
}

// ---------------- fused Set2Set step: LSTM + escore + online-softmax readout ----------------
// one block (64 threads = 1 wave) per graph b; hl/cl/qstar updated in place (per-block rows).
__global__ __launch_bounds__(64) void k_s2s(const float* __restrict__ node,
                                            const int* __restrict__ batch,
                                            const float* __restrict__ WihT2,
                                            const float* __restrict__ WhhT2,
                                            const float* __restrict__ bih,
                                            const float* __restrict__ bhh,
                                            float* __restrict__ cl,
                                            float* __restrict__ hl,
                                            float* __restrict__ qstar) {
    __shared__ float qvs[128];
    __shared__ float hls[64];
    const int b = blockIdx.x, lane = threadIdx.x;

    qvs[lane] = qstar[(size_t)b * 128 + lane];
    qvs[64 + lane] = qstar[(size_t)b * 128 + 64 + lane];
    hls[lane] = hl[(size_t)b * 64 + lane];
    __syncthreads();

    // LSTM gates: acc[gg] over q (128) and hl (64); weight rows coalesced
    float acc0 = bih[lane] + bhh[lane];
    float acc1 = bih[64 + lane] + bhh[64 + lane];
    float acc2 = bih[128 + lane] + bhh[128 + lane];
    float acc3 = bih[192 + lane] + bhh[192 + lane];
    for (int j = 0; j < 128; j++) {
        float qj = qvs[j];
        const float* wr = WihT2 + (size_t)j * 256;
        acc0 += qj * wr[lane];
        acc1 += qj * wr[64 + lane];
        acc2 += qj * wr[128 + lane];
        acc3 += qj * wr[192 + lane];
    }
    for (int j = 0; j < 64; j++) {
        float hj = hls[j];
        const float* wr = WhhT2 + (size_t)j * 256;
        acc0 += hj * wr[lane];
        acc1 += hj * wr[64 + lane];
        acc2 += hj * wr[128 + lane];
        acc3 += hj * wr[192 + lane];
    }
    float c = sigm(acc1) * cl[(size_t)b * 64 + lane] + sigm(acc0) * tanhf(acc2);
    cl[(size_t)b * 64 + lane] = c;
    float q = sigm(acc3) * tanhf(c);
    hl[(size_t)b * 64 + lane] = q;

    // segment bounds (binary search over sorted batch)
    int lo = 0, hi = NN_;
    while (lo < hi) { int mid = (lo + hi) >> 1; if (batch[mid] < b) lo = mid + 1; else hi = mid; }
    int start = lo;
    lo = start; hi = NN_;
    while (lo < hi) { int mid = (lo + hi) >> 1; if (batch[mid] < b + 1) lo = mid + 1; else hi = mid; }
    int end = lo;

    // online softmax readout: one coalesced node-row read serves dot AND accumulate
    float r_acc = 0.f, m_run = -1e30f, l_run = 0.f;
    for (int n = start; n < end; n++) {
        float nv = node[(size_t)n * 64 + lane];
        float p = nv * q;
#pragma unroll
        for (int o = 32; o > 0; o >>= 1) p += __shfl_xor(p, o);
        float m_new = fmaxf(m_run, p);
        float sc = expf(m_run - m_new);
        float wgt = expf(p - m_new);
        l_run = l_run * sc + wgt;
        r_acc = r_acc * sc + wgt * nv;
        m_run = m_new;
    }
    qstar[(size_t)b * 128 + lane] = q;
    qstar[(size_t)b * 128 + 64 + lane] = (end > start) ? r_acc / l_run : 0.f;
}

// ---------------- head ----------------
__global__ void k_fc(const float* qstar, const float* W1, const float* b1,
                     const float* W2, const float* b2, float* out) {
    __shared__ float hid[128];
    int b = blockIdx.x; int t = threadIdx.x;  // 128 threads
    const float* qr = qstar + (size_t)b * 128;
    float acc = b1[t];
    const float* wr = W1 + (size_t)t * 128;
    for (int k = 0; k < 128; k++) acc += qr[k] * wr[k];
    hid[t] = fmaxf(acc, 0.f);
    __syncthreads();
    if (t < 64) {
        float s = hid[t] * W2[t] + hid[t + 64] * W2[t + 64];
        for (int o = 32; o > 0; o >>= 1) s += __shfl_xor(s, o);
        if (t == 0) out[b] = s + b2[0];
    }
}

extern "C" void kernel_launch(void* const* d_in, const int* in_sizes, int n_in,
                              void* d_out, int out_size, void* d_ws, size_t ws_size,
                              hipStream_t stream) {
    const float* x     = (const float*)d_in[0];
    const int*   ei    = (const int*)d_in[1];
    const float* ea    = (const float*)d_in[2];
    const int*   batch = (const int*)d_in[3];
    const float* lin0W = (const float*)d_in[4];
    const float* lin0b = (const float*)d_in[5];
    const float* e1W   = (const float*)d_in[6];
    const float* e1b   = (const float*)d_in[7];
    const float* e2W   = (const float*)d_in[8];
    const float* e2b   = (const float*)d_in[9];
    const float* rootW = (const float*)d_in[10];
    const float* convb = (const float*)d_in[11];
    const float* gWih  = (const float*)d_in[12];
    const float* gWhh  = (const float*)d_in[13];
    const float* gbih  = (const float*)d_in[14];
    const float* gbhh  = (const float*)d_in[15];
    const float* lWih  = (const float*)d_in[16];
    const float* lWhh  = (const float*)d_in[17];
    const float* lbih  = (const float*)d_in[18];
    const float* lbhh  = (const float*)d_in[19];
    const float* fc1W  = (const float*)d_in[20];
    const float* fc1b  = (const float*)d_in[21];
    const float* fc2W  = (const float*)d_in[22];
    const float* fc2b  = (const float*)d_in[23];
    const int* src = ei;
    const int* dst = ei + NE_;

    // workspace carve (~41 MB)
    char* p = (char*)d_ws;
    auto alloc = [&](size_t bytes) -> char* {
        char* r = p; p += (bytes + 255) & ~(size_t)255; return r;
    };
    unsigned short* Bhat3 = (unsigned short*)alloc((size_t)524288 * 2);        // 1.05 MB
    unsigned short* Hhat  = (unsigned short*)alloc((size_t)NE_ * 128 * 2);     // 12.6 MB
    float* nodeA  = (float*)alloc((size_t)NN_ * 64 * 4);
    float* nodeB  = (float*)alloc((size_t)NN_ * 64 * 4);
    float* aggb   = (float*)alloc((size_t)NN_ * 64 * 4);
    float* cnt    = (float*)alloc((size_t)NN_ * 4);
    float* WihT   = (float*)alloc(192 * 64 * 4);
    float* WhhT   = (float*)alloc(192 * 64 * 4);
    float* WihT2  = (float*)alloc(256 * 128 * 4);
    float* WhhT2  = (float*)alloc(256 * 64 * 4);
    float* qstar  = (float*)alloc((size_t)NG_ * 128 * 4);  // qstar | hl | cl contiguous
    float* hl     = (float*)alloc((size_t)NG_ * 64 * 4);
    float* clb    = (float*)alloc((size_t)NG_ * 64 * 4);

    k_init<<<(NN_ + NG_ * 256 + 255) / 256, 256, 0, stream>>>(cnt, qstar);
    k_lin0<<<NN_ * 64 / 256, 256, 0, stream>>>(x, lin0W, lin0b, nodeA);
    k_cnt<<<NE_ / 256, 256, 0, stream>>>(dst, cnt);
    k_tw<<<288, 256, 0, stream>>>(gWih, gWhh, WihT, WhhT, lWih, lWhh, WihT2, WhhT2);
    k_bhat3<<<524288 / 256, 256, 0, stream>>>(e2W, Bhat3);
    k_he<<<NE_ / 16, 256, 0, stream>>>(ea, e1W, e1b, Hhat);   // once — iteration-invariant

    float* curF = nodeA; float* nxtF = nodeB;
    for (int it = 0; it < 3; it++) {
        k_zero<<<NN_ * 64 / 256, 256, 0, stream>>>(aggb, NN_ * 64);
        k_convr<<<NE_ / 32, 256, 0, stream>>>(curF, Hhat, Bhat3, e2b, src, dst, aggb);
        k_mgru<<<NN_ / 16, 256, 0, stream>>>(aggb, cnt, curF, rootW, convb,
                                             WihT, WhhT, gbih, gbhh, nxtF);
        float* tf = curF; curF = nxtF; nxtF = tf;
    }

    for (int s = 0; s < 3; s++)
        k_s2s<<<NG_, 64, 0, stream>>>(curF, batch, WihT2, WhhT2, lbih, lbhh, clb, hl, qstar);
    k_fc<<<NG_, 128, 0, stream>>>(qstar, fc1W, fc1b, fc2W, fc2b, (float*)d_out);
}

// Round 4
// 514.147 us; speedup vs baseline: 1.3709x; 1.3709x over previous
//
#include <hip/hip_runtime.h>
#include <math.h>

#define NN_ 32768      // nodes
#define NE_ 49152      // edges
#define NG_ 1024       // graphs

typedef short bh8 __attribute__((ext_vector_type(8)));   // 8 bf16 bit-patterns (4 VGPR)
typedef float f32x4 __attribute__((ext_vector_type(4)));

__device__ __forceinline__ unsigned short f2bfu(float f) {   // RNE float->bf16 bits
    union { float f; unsigned int i; } x; x.f = f;
    unsigned int u = x.i;
    u += 0x7FFFu + ((u >> 16) & 1u);
    return (unsigned short)(u >> 16);
}
__device__ __forceinline__ float sigm(float x) { return 1.f / (1.f + expf(-x)); }

// Kept for harness compatibility (unused).
__global__ void MPNN_78632261256134_kernel() {}

// ---------------- zero fill ----------------
__global__ void k_zero(float* p, int n) {
    int i = blockIdx.x * 256 + threadIdx.x;
    if (i < n) p[i] = 0.f;
}

// ---------------- fused init zero: cnt (NN_) + qstar|hl|cl (NG_*256) ----------------
__global__ void k_init(float* cnt, float* qstar) {
    int i = blockIdx.x * 256 + threadIdx.x;
    if (i < NN_) cnt[i] = 0.f;
    else if (i < NN_ + NG_ * 256) qstar[i - NN_] = 0.f;
}

// ---------------- lin0 ----------------
__global__ void k_lin0(const float* x, const float* W, const float* b, float* node) {
    int g = blockIdx.x * 256 + threadIdx.x;   // n*64+d
    int n = g >> 6, d = g & 63;
    const float* xr = x + n * 14;
    const float* wr = W + d * 14;
    float acc = b[d];
    for (int i = 0; i < 14; i++) acc += xr[i] * wr[i];
    node[g] = fmaxf(acc, 0.f);
}

// ---------------- in-degree count ----------------
__global__ void k_cnt(const int* dst, float* cnt) {
    int e = blockIdx.x * 256 + threadIdx.x;
    if (e < NE_) atomicAdd(&cnt[dst[e]], 1.0f);
}

// ---------------- fused weight transposes (4 kernels -> 1) ----------------
// [0,12288): gWih [192,64]->WihT [64,192]; [12288,24576): gWhh likewise;
// [24576,57344): lWih [256,128]->WihT2 [128,256]; [57344,73728): lWhh [256,64]->WhhT2 [64,256]
__global__ void k_tw(const float* gWih, const float* gWhh, float* WihT, float* WhhT,
                     const float* lWih, const float* lWhh, float* WihT2, float* WhhT2) {
    int t = blockIdx.x * 256 + threadIdx.x;
    if (t < 12288) {
        int gr = t >> 6, i = t & 63; WihT[i * 192 + gr] = gWih[t];
    } else if (t < 24576) {
        int u = t - 12288; int gr = u >> 6, i = u & 63; WhhT[i * 192 + gr] = gWhh[u];
    } else if (t < 57344) {
        int u = t - 24576; int r = u >> 7, c = u & 127; WihT2[c * 256 + r] = lWih[u];
    } else if (t < 73728) {
        int u = t - 57344; int r = u >> 6, c = u & 63; WhhT2[c * 256 + r] = lWhh[u];
    }
}

// ---------------- Bhat3: frag-contiguous bf16 B [s][w][t][lane][8] ----------------
__global__ void k_bhat3(const float* e2W, unsigned short* Bhat3) {
    int idx = blockIdx.x * 256 + threadIdx.x;   // < 524288
    if (idx >= 64 * 4 * 4 * 64 * 8) return;
    int j = idx & 7, lane = (idx >> 3) & 63, t = (idx >> 9) & 3, w = (idx >> 11) & 3, s = idx >> 13;
    int row = s * 64 + w * 16 + (lane & 15);
    int k = t * 32 + (lane >> 4) * 8 + j;
    Bhat3[idx] = f2bfu(e2W[row * 128 + k]);
}

// ---------------- Hhat: frag-ready He (iteration-invariant, computed once) ----------------
// gi = etile*4+t; grid must cover gi < (NE_/16)*4 = 12288 -> NE_/16 blocks of 4 gi.
__global__ __launch_bounds__(256) void k_he(const float* __restrict__ ea,
                                            const float* __restrict__ e1W,
                                            const float* __restrict__ e1b,
                                            unsigned short* __restrict__ Hhat) {
    int tid = threadIdx.x;
    int lane = tid & 63, sub = tid >> 6;
    int gi = blockIdx.x * 4 + sub;            // < 12288
    int etile = gi >> 2, t = gi & 3;
    int e = etile * 16 + (lane & 15), quad = lane >> 4;
    const float* ar = ea + (size_t)e * 4;
    float a0 = ar[0], a1 = ar[1], a2 = ar[2], a3 = ar[3];
    union { unsigned short u[8]; uint4 q; } o;
#pragma unroll
    for (int j = 0; j < 8; j++) {
        int c = t * 32 + quad * 8 + j;
        const float* wr = e1W + c * 4;
        float h = e1b[c] + a0 * wr[0] + a1 * wr[1] + a2 * wr[2] + a3 * wr[3];
        o.u[j] = f2bfu(fmaxf(h, 0.f));
    }
    *(uint4*)(Hhat + (size_t)gi * 512 + lane * 8) = o.q;
}

// ---------------- MFMA NNConv: round-0 structure + in-wave software pipelining ----------------
// Per s-step the wave issues 16 MFMAs into ONE acc buffer, then consumes the OTHER acc
// buffer (results of s-1) in VALU. The acc dependency distance is a full iteration
// (~256+ matrix-pipe cycles), so the VALU consume never interlocks on in-flight MFMAs
// and the matrix pipe stays fed during the consume phase. e2b is staged in LDS so the
// inner loop touches only LDS + L2-resident Bhat3.
#define LDB(B, S) {                                                                       \
        const unsigned short* _p = Bhat3 + (size_t)(S) * 8192 + w * 2048 + lane * 8;      \
        (B)[0] = *(const bh8*)(const void*)(_p);                                          \
        (B)[1] = *(const bh8*)(const void*)(_p + 512);                                    \
        (B)[2] = *(const bh8*)(const void*)(_p + 1024);                                   \
        (B)[3] = *(const bh8*)(const void*)(_p + 1536); }

#define MFMA16(ACC, B) {                                                                  \
        _Pragma("unroll")                                                                 \
        for (int t_ = 0; t_ < 4; t_++) {                                                  \
            _Pragma("unroll")                                                             \
            for (int mt_ = 0; mt_ < 4; mt_++)                                             \
                (ACC)[mt_] = __builtin_amdgcn_mfma_f32_16x16x32_bf16(                     \
                    af[mt_][t_], (B)[t_], (t_ == 0) ? z4 : (ACC)[mt_], 0, 0, 0);          \
        } }

#define CONSUME(ACC, S) {                                                                 \
        float bb_ = ebs[(S) * 64 + w * 16 + mrow];                                        \
        _Pragma("unroll")                                                                 \
        for (int mt_ = 0; mt_ < 4; mt_++) {                                               \
            f32x4 xv_ = *(const f32x4*)(const void*)(xs + (S) * 68 + mt_ * 16 + quad * 4);\
            _Pragma("unroll")                                                             \
            for (int r_ = 0; r_ < 4; r_++)                                                \
                msg[mt_][r_] += xv_[r_] * ((ACC)[mt_][r_] + bb_);                         \
        } }

__global__ __launch_bounds__(256) void k_convr(const float* __restrict__ node,
                                               const unsigned short* __restrict__ Hhat,
                                               const unsigned short* __restrict__ Bhat3,
                                               const float* __restrict__ e2b,
                                               const int* __restrict__ src,
                                               const int* __restrict__ dst,
                                               float* __restrict__ agg) {
    __shared__ __align__(16) float xs[64 * 68];   // xs[s][e]
    __shared__ __align__(16) float ebs[64 * 64];  // e2b staged [s][o]
    __shared__ int dst_s[64];

    const int tid = threadIdx.x;
    const int eb = blockIdx.x * 64;
    const int lane = tid & 63, w = tid >> 6;
    const int quad = lane >> 4, mrow = lane & 15;

    {
        int r = tid >> 2, c = tid & 3;
        int s = src[eb + r];
        const float* nr = node + (size_t)s * 64 + c * 16;
#pragma unroll
        for (int j = 0; j < 16; j++) xs[(c * 16 + j) * 68 + r] = nr[j];
#pragma unroll
        for (int j = 0; j < 16; j++) ebs[tid + 256 * j] = e2b[tid + 256 * j];
        if (tid < 64) dst_s[tid] = dst[eb + tid];
    }

    bh8 af[4][4];
#pragma unroll
    for (int mt = 0; mt < 4; mt++)
#pragma unroll
        for (int t = 0; t < 4; t++)
            af[mt][t] = *(const bh8*)(const void*)(
                Hhat + (size_t)(((eb >> 4) + mt) * 4 + t) * 512 + lane * 8);
    __syncthreads();   // the ONLY barrier

    const f32x4 z4 = {0.f, 0.f, 0.f, 0.f};
    f32x4 msg[4];
#pragma unroll
    for (int mt = 0; mt < 4; mt++) msg[mt] = z4;

    bh8 b0[4], b1[4];
    f32x4 accA[4], accB[4];

    // prologue: s=0 in flight, B(1) loaded
    LDB(b0, 0)
    MFMA16(accA, b0)
    LDB(b1, 1)

    for (int s = 0; s < 62; s += 2) {
        MFMA16(accB, b1)        // issue s+1 MFMAs first...
        LDB(b0, s + 2)
        CONSUME(accA, s)        // ...then consume s (no interlock; overlaps s+1 MFMAs)
        MFMA16(accA, b0)        // issue s+2
        LDB(b1, s + 3)
        CONSUME(accB, s + 1)    // consume s+1 (overlaps s+2 MFMAs)
    }
    // epilogue: accA holds s=62 (issued), b1 = B(63)
    MFMA16(accB, b1)            // s=63
    CONSUME(accA, 62)
    CONSUME(accB, 63)

#pragma unroll
    for (int mt = 0; mt < 4; mt++)
#pragma unroll
        for (int r = 0; r < 4; r++)
            atomicAdd(agg + (size_t)dst_s[mt * 16 + quad * 4 + r] * 64 + w * 16 + mrow,
                      msg[mt][r]);
}

// ---------------- fused m+GRU, transposed LDS (broadcast b128 reads) ----------------
// 16 nodes/block, thread (sub=tid>>6, d=tid&63) handles nodes sub*4..+3 at dim d.
// msT/hsT are [i][node] stride 20 -> wave-wide reads of msT[i][r0..r0+3] are broadcast b128.
__global__ __launch_bounds__(256) void k_mgru(const float* __restrict__ agg,
                                              const float* __restrict__ cnt,
                                              const float* __restrict__ node,
                                              const float* __restrict__ rootW,
                                              const float* __restrict__ convb,
                                              const float* __restrict__ WihT,
                                              const float* __restrict__ WhhT,
                                              const float* __restrict__ bih,
                                              const float* __restrict__ bhh,
                                              float* __restrict__ hOut) {
    __shared__ __align__(16) float hsT[64][20];   // hsT[i][node]
    __shared__ __align__(16) float msT[64][20];
    const int tid = threadIdx.x;
    const int d = tid & 63, sub = tid >> 6;
    const int nb = blockIdx.x * 16;
    const int r0 = sub * 4;

    {   // stage h transposed: coalesced global reads, one b128 LDS store
        f32x4 hv;
#pragma unroll
        for (int j = 0; j < 4; j++)
            hv[j] = node[(size_t)(nb + r0 + j) * 64 + d];
        *(f32x4*)&hsT[d][r0] = hv;
    }
    __syncthreads();

    {   // m = relu(agg/cnt + h@rootW + convb); rootW load shared, hsT broadcast
        f32x4 root = {0.f, 0.f, 0.f, 0.f};
        for (int i = 0; i < 64; i++) {
            float wv = rootW[i * 64 + d];
            f32x4 h4 = *(const f32x4*)&hsT[i][r0];
#pragma unroll
            for (int j = 0; j < 4; j++) root[j] += h4[j] * wv;
        }
        float cb = convb[d];
        f32x4 mval;
#pragma unroll
        for (int j = 0; j < 4; j++) {
            int n = nb + r0 + j;
            float inv = 1.f / fmaxf(cnt[n], 1.f);
            mval[j] = fmaxf(agg[(size_t)n * 64 + d] * inv + cb + root[j], 0.f);
        }
        *(f32x4*)&msT[d][r0] = mval;
    }
    __syncthreads();

    float ir[4], iz[4], in_[4], hr[4], hz[4], hn[4];
    {
        float bi0 = bih[d], bi1 = bih[64 + d], bi2 = bih[128 + d];
        float bh0 = bhh[d], bh1 = bhh[64 + d], bh2 = bhh[128 + d];
#pragma unroll
        for (int j = 0; j < 4; j++) {
            ir[j] = bi0; iz[j] = bi1; in_[j] = bi2;
            hr[j] = bh0; hz[j] = bh1; hn[j] = bh2;
        }
    }
    for (int i = 0; i < 64; i++) {
        float wi0 = WihT[i * 192 + d];
        float wi1 = WihT[i * 192 + 64 + d];
        float wi2 = WihT[i * 192 + 128 + d];
        float wh0 = WhhT[i * 192 + d];
        float wh1 = WhhT[i * 192 + 64 + d];
        float wh2 = WhhT[i * 192 + 128 + d];
        f32x4 m4 = *(const f32x4*)&msT[i][r0];   // broadcast
        f32x4 h4 = *(const f32x4*)&hsT[i][r0];   // broadcast
#pragma unroll
        for (int j = 0; j < 4; j++) {
            ir[j] += m4[j] * wi0; iz[j] += m4[j] * wi1; in_[j] += m4[j] * wi2;
            hr[j] += h4[j] * wh0; hz[j] += h4[j] * wh1; hn[j] += h4[j] * wh2;
        }
    }
    f32x4 hold = *(const f32x4*)&hsT[d][r0];
#pragma unroll
    for (int j = 0; j < 4; j++) {
        float r = sigm(ir[j] + hr[j]);
        float z = sigm(iz[j] + hz[j]);
        float nn = tanhf(in_[j] + r * hn[j]);
        hOut[(size_t)(nb + r0 + j) * 64 + d] = (1.f - z) * nn + z * hold[j];
    }
}

// ---------------- fused Set2Set step: LSTM + escore + online-softmax readout ----------------
// one block (64 threads = 1 wave) per graph b; hl/cl/qstar updated in place (per-block rows).
__global__ __launch_bounds__(64) void k_s2s(const float* __restrict__ node,
                                            const int* __restrict__ batch,
                                            const float* __restrict__ WihT2,
                                            const float* __restrict__ WhhT2,
                                            const float* __restrict__ bih,
                                            const float* __restrict__ bhh,
                                            float* __restrict__ cl,
                                            float* __restrict__ hl,
                                            float* __restrict__ qstar) {
    __shared__ float qvs[128];
    __shared__ float hls[64];
    const int b = blockIdx.x, lane = threadIdx.x;

    qvs[lane] = qstar[(size_t)b * 128 + lane];
    qvs[64 + lane] = qstar[(size_t)b * 128 + 64 + lane];
    hls[lane] = hl[(size_t)b * 64 + lane];
    __syncthreads();

    // LSTM gates: acc[gg] over q (128) and hl (64); weight rows coalesced
    float acc0 = bih[lane] + bhh[lane];
    float acc1 = bih[64 + lane] + bhh[64 + lane];
    float acc2 = bih[128 + lane] + bhh[128 + lane];
    float acc3 = bih[192 + lane] + bhh[192 + lane];
    for (int j = 0; j < 128; j++) {
        float qj = qvs[j];
        const float* wr = WihT2 + (size_t)j * 256;
        acc0 += qj * wr[lane];
        acc1 += qj * wr[64 + lane];
        acc2 += qj * wr[128 + lane];
        acc3 += qj * wr[192 + lane];
    }
    for (int j = 0; j < 64; j++) {
        float hj = hls[j];
        const float* wr = WhhT2 + (size_t)j * 256;
        acc0 += hj * wr[lane];
        acc1 += hj * wr[64 + lane];
        acc2 += hj * wr[128 + lane];
        acc3 += hj * wr[192 + lane];
    }
    float c = sigm(acc1) * cl[(size_t)b * 64 + lane] + sigm(acc0) * tanhf(acc2);
    cl[(size_t)b * 64 + lane] = c;
    float q = sigm(acc3) * tanhf(c);
    hl[(size_t)b * 64 + lane] = q;

    // segment bounds (binary search over sorted batch)
    int lo = 0, hi = NN_;
    while (lo < hi) { int mid = (lo + hi) >> 1; if (batch[mid] < b) lo = mid + 1; else hi = mid; }
    int start = lo;
    lo = start; hi = NN_;
    while (lo < hi) { int mid = (lo + hi) >> 1; if (batch[mid] < b + 1) lo = mid + 1; else hi = mid; }
    int end = lo;

    // online softmax readout: one coalesced node-row read serves dot AND accumulate
    float r_acc = 0.f, m_run = -1e30f, l_run = 0.f;
    for (int n = start; n < end; n++) {
        float nv = node[(size_t)n * 64 + lane];
        float p = nv * q;
#pragma unroll
        for (int o = 32; o > 0; o >>= 1) p += __shfl_xor(p, o);
        float m_new = fmaxf(m_run, p);
        float sc = expf(m_run - m_new);
        float wgt = expf(p - m_new);
        l_run = l_run * sc + wgt;
        r_acc = r_acc * sc + wgt * nv;
        m_run = m_new;
    }
    qstar[(size_t)b * 128 + lane] = q;
    qstar[(size_t)b * 128 + 64 + lane] = (end > start) ? r_acc / l_run : 0.f;
}

// ---------------- head ----------------
__global__ void k_fc(const float* qstar, const float* W1, const float* b1,
                     const float* W2, const float* b2, float* out) {
    __shared__ float hid[128];
    int b = blockIdx.x; int t = threadIdx.x;  // 128 threads
    const float* qr = qstar + (size_t)b * 128;
    float acc = b1[t];
    const float* wr = W1 + (size_t)t * 128;
    for (int k = 0; k < 128; k++) acc += qr[k] * wr[k];
    hid[t] = fmaxf(acc, 0.f);
    __syncthreads();
    if (t < 64) {
        float s = hid[t] * W2[t] + hid[t + 64] * W2[t + 64];
        for (int o = 32; o > 0; o >>= 1) s += __shfl_xor(s, o);
        if (t == 0) out[b] = s + b2[0];
    }
}

extern "C" void kernel_launch(void* const* d_in, const int* in_sizes, int n_in,
                              void* d_out, int out_size, void* d_ws, size_t ws_size,
                              hipStream_t stream) {
    const float* x     = (const float*)d_in[0];
    const int*   ei    = (const int*)d_in[1];
    const float* ea    = (const float*)d_in[2];
    const int*   batch = (const int*)d_in[3];
    const float* lin0W = (const float*)d_in[4];
    const float* lin0b = (const float*)d_in[5];
    const float* e1W   = (const float*)d_in[6];
    const float* e1b   = (const float*)d_in[7];
    const float* e2W   = (const float*)d_in[8];
    const float* e2b   = (const float*)d_in[9];
    const float* rootW = (const float*)d_in[10];
    const float* convb = (const float*)d_in[11];
    const float* gWih  = (const float*)d_in[12];
    const float* gWhh  = (const float*)d_in[13];
    const float* gbih  = (const float*)d_in[14];
    const float* gbhh  = (const float*)d_in[15];
    const float* lWih  = (const float*)d_in[16];
    const float* lWhh  = (const float*)d_in[17];
    const float* lbih  = (const float*)d_in[18];
    const float* lbhh  = (const float*)d_in[19];
    const float* fc1W  = (const float*)d_in[20];
    const float* fc1b  = (const float*)d_in[21];
    const float* fc2W  = (const float*)d_in[22];
    const float* fc2b  = (const float*)d_in[23];
    const int* src = ei;
    const int* dst = ei + NE_;

    // workspace carve (~41 MB)
    char* p = (char*)d_ws;
    auto alloc = [&](size_t bytes) -> char* {
        char* r = p; p += (bytes + 255) & ~(size_t)255; return r;
    };
    unsigned short* Bhat3 = (unsigned short*)alloc((size_t)524288 * 2);        // 1.05 MB
    unsigned short* Hhat  = (unsigned short*)alloc((size_t)NE_ * 128 * 2);     // 12.6 MB
    float* nodeA  = (float*)alloc((size_t)NN_ * 64 * 4);
    float* nodeB  = (float*)alloc((size_t)NN_ * 64 * 4);
    float* aggb   = (float*)alloc((size_t)NN_ * 64 * 4);
    float* cnt    = (float*)alloc((size_t)NN_ * 4);
    float* WihT   = (float*)alloc(192 * 64 * 4);
    float* WhhT   = (float*)alloc(192 * 64 * 4);
    float* WihT2  = (float*)alloc(256 * 128 * 4);
    float* WhhT2  = (float*)alloc(256 * 64 * 4);
    float* qstar  = (float*)alloc((size_t)NG_ * 128 * 4);  // qstar | hl | cl contiguous
    float* hl     = (float*)alloc((size_t)NG_ * 64 * 4);
    float* clb    = (float*)alloc((size_t)NG_ * 64 * 4);

    k_init<<<(NN_ + NG_ * 256 + 255) / 256, 256, 0, stream>>>(cnt, qstar);
    k_lin0<<<NN_ * 64 / 256, 256, 0, stream>>>(x, lin0W, lin0b, nodeA);
    k_cnt<<<NE_ / 256, 256, 0, stream>>>(dst, cnt);
    k_tw<<<288, 256, 0, stream>>>(gWih, gWhh, WihT, WhhT, lWih, lWhh, WihT2, WhhT2);
    k_bhat3<<<524288 / 256, 256, 0, stream>>>(e2W, Bhat3);
    k_he<<<NE_ / 16, 256, 0, stream>>>(ea, e1W, e1b, Hhat);   // once — iteration-invariant

    float* curF = nodeA; float* nxtF = nodeB;
    for (int it = 0; it < 3; it++) {
        k_zero<<<NN_ * 64 / 256, 256, 0, stream>>>(aggb, NN_ * 64);
        k_convr<<<NE_ / 64, 256, 0, stream>>>(curF, Hhat, Bhat3, e2b, src, dst, aggb);
        k_mgru<<<NN_ / 16, 256, 0, stream>>>(aggb, cnt, curF, rootW, convb,
                                             WihT, WhhT, gbih, gbhh, nxtF);
        float* tf = curF; curF = nxtF; nxtF = tf;
    }

    for (int s = 0; s < 3; s++)
        k_s2s<<<NG_, 64, 0, stream>>>(curF, batch, WihT2, WhhT2, lbih, lbhh, clb, hl, qstar);
    k_fc<<<NG_, 128, 0, stream>>>(qstar, fc1W, fc1b, fc2W, fc2b, (float*)d_out);
}